// Round 8
// baseline (121.545 us; speedup 1.0000x reference)
//
#include <hip/hip_runtime.h>

typedef __bf16 bf16x8 __attribute__((ext_vector_type(8)));
typedef float f32x16 __attribute__((ext_vector_type(16)));

#define GLDS(gp, lp) __builtin_amdgcn_global_load_lds( \
    (const __attribute__((address_space(1))) void*)(gp), \
    (__attribute__((address_space(3))) void*)(lp), 16, 0, 0)
#define WAITV(n) asm volatile("s_waitcnt vmcnt(" #n ")" ::: "memory")
#define MEMF() asm volatile("" ::: "memory")

__device__ __forceinline__ unsigned short f2bf(float f) {
    unsigned int u = __builtin_bit_cast(unsigned int, f);
    u += 0x7fffu + ((u >> 16) & 1u);
    return (unsigned short)(u >> 16);
}

// ---- Fused prep: style (blocks 0..3), border-zero (4..133), packw (134..645) ----
__global__ __launch_bounds__(512) void k_prep(const float* __restrict__ style,
                                              const float* __restrict__ aw,
                                              const float* __restrict__ ab,
                                              const float* __restrict__ wsrc,
                                              float* __restrict__ s_eff,
                                              unsigned short* __restrict__ xmod,
                                              unsigned short* __restrict__ wpk3) {
    int bid = blockIdx.x, t = threadIdx.x;
    if (bid < 4) {
        int b = bid, i = t;
        __shared__ float st[512];
        st[i] = style[(b << 9) + i];
        __syncthreads();
        const float4* row = (const float4*)(aw + ((size_t)i << 9));
        float acc = 0.f;
#pragma unroll 4
        for (int k = 0; k < 128; ++k) {
            float4 r = row[k];
            acc += r.x * st[4 * k] + r.y * st[4 * k + 1] + r.z * st[4 * k + 2] + r.w * st[4 * k + 3];
        }
        float s = acc * 0.04419417382415922f + ab[i];
        s_eff[(b << 9) + i] = s * 0.014731391274719739f;
    } else if (bid < 134) {
        int idx = (bid - 4) * 512 + t;          // 0..66559
        int cell = idx >> 6, sub = idx & 63;
        int b = cell / 260, c = cell - b * 260;
        int row, col;
        if (c < 66)       { row = 0;  col = c; }
        else if (c < 132) { row = 65; col = c - 66; }
        else { int d = c - 132; row = 1 + (d >> 1); col = (d & 1) * 65; }
        uint4 z; z.x = z.y = z.z = z.w = 0u;
        *(uint4*)(xmod + (((size_t)(b * 66 + row) * 66 + col) << 9) + (sub << 3)) = z;
    } else {
        // weight (O,I,3,3) -> wpk3 for 32x32x16 fragments:
        // [mt][s=ic*9+r][strip 0..3][kk 0..1][lane 0..63][8ch]
        // A-frag mapping: row = lane&31, k16 = (lane>>5)*8 + j
        int o = bid - 134;
        int mt = o >> 7, om = o & 127, strip = om >> 5, orow = om & 31;
        int i = t;
        int ic = i >> 5, kk = (i >> 4) & 1, half = (i >> 3) & 1, j = i & 7;
        int lane = orow + (half << 5);
        const float* src = wsrc + (size_t)((o << 9) + i) * 9;
        unsigned short* dst = wpk3 + (((((size_t)mt * 144 + ic * 9) * 4 + strip) * 2 + kk) << 9)
                              + (lane << 3) + j;
#pragma unroll
        for (int r = 0; r < 9; ++r)
            dst[r * 4096] = f2bf(src[r]);
    }
}

// ---- packx: x (NCHW f32) -> xmod (padded NHWC bf16), modulated. COALESCED loads + LDS transpose. ----
__global__ __launch_bounds__(256) void k_packx(const float* __restrict__ x,
                                               const float* __restrict__ s_eff,
                                               unsigned short* __restrict__ xmod) {
    int b = blockIdx.z, h = blockIdx.y, i0 = blockIdx.x << 6;
    __shared__ unsigned short tile[64][72];
    int t = threadIdx.x;
    int wq = t & 15;     // w-quad: lanes low bits -> contiguous 16B x 16 lanes = 256B coalesced
    int ch = t >> 4;     // 16 channels per pass
#pragma unroll
    for (int p = 0; p < 4; ++p) {
        int il = (p << 4) + ch;
        int i = i0 + il;
        float4 v = *(const float4*)(x + (size_t)((((b << 9) + i) << 6) + h) * 64 + (wq << 2));
        float s = s_eff[(b << 9) + i];
        union { unsigned short us[4]; uint2 u2; } u;
        u.us[0] = f2bf(v.x * s); u.us[1] = f2bf(v.y * s);
        u.us[2] = f2bf(v.z * s); u.us[3] = f2bf(v.w * s);
        *(uint2*)&tile[il][wq << 2] = u.u2;
    }
    __syncthreads();
    int ib = (t & 7) << 3;
    int wb = t >> 3;
#pragma unroll
    for (int pass = 0; pass < 2; ++pass) {
        int w = wb + (pass << 5);
        union { unsigned short us[8]; uint4 v; } u;
#pragma unroll
        for (int j = 0; j < 8; ++j) u.us[j] = tile[ib + j][w];
        *(uint4*)(xmod + (((size_t)(b * 66 + h + 1) * 66 + (w + 1)) << 9) + i0 + ib) = u.v;
    }
}

// ---- k_conv: implicit GEMM, 32x32x16 MFMA. Block 128(O) x 128(N = 2 rows x 64 w), 4 waves 2x2,
// wave tile 64x64 = 2x2 tiles of 32x32. Grid 512, 2 blocks/CU (2 waves/SIMD).
// A: coalesced global->VGPR (L2-resident, fragment-linear), 3-slot rotation, 2 steps ahead.
// B: global_load_lds double-buffer, issued at r==4 (T4 counted vmcnt), T2 slot-swizzle,
//    bfr register double-buffer prefetched ONE STEP ahead (kills per-step lgkm stall).
// ONE barrier + WAITV(4) per 32-ch chunk.
__global__ __launch_bounds__(256, 2) void k_conv(const unsigned short* __restrict__ xmod,
                                                 const unsigned short* __restrict__ wpk3,
                                                 float* __restrict__ out) {
    __shared__ __attribute__((aligned(128))) unsigned char lds[2][17408];

    int bid = blockIdx.x;
    int swz = ((bid & 7) << 6) | (bid >> 3);     // XCD swizzle (512 = 8*64, bijective)
    int mt = swz >> 7, nt = swz & 127;
    int b = nt >> 5, h0 = (nt & 31) << 1;
    int m0 = mt << 7;
    int tid = threadIdx.x;
    int lane = tid & 63;
    int wv = tid >> 6;
    int wm = wv & 1, wn = wv >> 1;               // wave tile 64x64
    int l31 = lane & 31, hi = lane >> 5;

    const unsigned char* xq = (const unsigned char*)xmod;

    // B global source offsets (pre-swizzled: 16B slot ^= (col>>1)&3)
    int bsrc[5];
#pragma unroll
    for (int q = 0; q < 5; ++q) {
        int c = q * 256 + tid; if (c > 1055) c = 1055;
        int cl = c >> 2, sub = c & 3;
        int row = cl / 66, col = cl - row * 66;
        int sub2 = sub ^ ((col >> 1) & 3);
        bsrc[q] = ((b * 66 + h0 + row) * 66 + col) * 1024 + (sub2 << 4);
    }

    // B LDS read offsets: tile tn, tap kw, k-half kk. col = tn*32 + l31 + kw; hl = wn.
    // slot = ((kk<<1)|hi) ^ ((col>>1)&3); every 8 consecutive lanes hit 8 distinct bank-starts.
    int boff[2][3][2];
#pragma unroll
    for (int tn = 0; tn < 2; ++tn)
#pragma unroll
        for (int kw = 0; kw < 3; ++kw)
#pragma unroll
            for (int kk = 0; kk < 2; ++kk) {
                int col = (tn << 5) + l31 + kw;
                int slot = ((kk << 1) | hi) ^ ((col >> 1) & 3);
                boff[tn][kw][kk] = wn * 4224 + col * 64 + (slot << 4);  // + kh*4224 at use
            }

    // A fragment stream: step s block = wbase + s*4096 el; within: (strip*2+kk)*512 + lane*8
    const unsigned short* wbase = wpk3 + ((size_t)mt * 144) * 4096;
    int aoff = (wm << 11) + (lane << 3);         // strip base = wm*2 -> wm*2*2*512 = wm*2048

    f32x16 acc[2][2] = {};
    bf16x8 af[3][2][2];
    bf16x8 bfr[2][2][2];

    // ---- prologue: issue B[0] (GLDS), load A[0],A[1] to regs ----
    {
        unsigned char* bd = &lds[0][0] + tid * 16;
        GLDS(xq + bsrc[0], bd);
        GLDS(xq + bsrc[1], bd + 4096);
        GLDS(xq + bsrc[2], bd + 8192);
        GLDS(xq + bsrc[3], bd + 12288);
        if (wv == 0) GLDS(xq + bsrc[4], &lds[0][0] + 16384);
    }
#pragma unroll
    for (int s = 0; s < 2; ++s)
#pragma unroll
        for (int tm = 0; tm < 2; ++tm)
#pragma unroll
            for (int kk = 0; kk < 2; ++kk)
                af[s][tm][kk] = *(const bf16x8*)(wbase + s * 4096 + aoff + tm * 1024 + kk * 512);

#pragma unroll 1
    for (int ic = 0; ic < 16; ++ic) {
        const unsigned char* Bb = &lds[ic & 1][0];
        unsigned char* Bn = &lds[(ic + 1) & 1][0];
#pragma unroll
        for (int r = 0; r < 9; ++r) {
            if (r == 0) {
                // own B chunks + af(prev r7) older than af(prev r8)'s 4 loads
                WAITV(4);
                __builtin_amdgcn_s_barrier();
                MEMF();
            }
            int s = ic * 9 + r;
            // prefetch A[s+2] into rotation slot (r+2)%3 (16KB slack covers tail overshoot)
            {
                const unsigned short* ap = wbase + (size_t)(s + 2) * 4096 + aoff;
#pragma unroll
                for (int tm = 0; tm < 2; ++tm)
#pragma unroll
                    for (int kk = 0; kk < 2; ++kk)
                        af[(r + 2) % 3][tm][kk] = *(const bf16x8*)(ap + tm * 1024 + kk * 512);
            }
            if (r == 4) {   // issue B[ic+1] (ic=15: harmless dummy into dead buffer)
                int icb = (ic + 1) << 6;
                unsigned char* bd = Bn + tid * 16;
                GLDS(xq + bsrc[0] + icb, bd);
                GLDS(xq + bsrc[1] + icb, bd + 4096);
                GLDS(xq + bsrc[2] + icb, bd + 8192);
                GLDS(xq + bsrc[3] + icb, bd + 12288);
                if (wv == 0) GLDS(xq + bsrc[4] + icb, Bn + 16384);
            }
            if (r == 0) {   // load own bfr (post-barrier; one exposed lgkm per chunk)
                int kh = 0;
#pragma unroll
                for (int tn = 0; tn < 2; ++tn)
#pragma unroll
                    for (int kk = 0; kk < 2; ++kk)
                        bfr[0][tn][kk] = *(const bf16x8*)(Bb + boff[tn][0][kk] + kh * 4224);
            }
            if (r < 8) {    // prefetch bfr for step r+1
                int r1 = r + 1;
                int kh1 = r1 / 3, kw1 = r1 - kh1 * 3;
#pragma unroll
                for (int tn = 0; tn < 2; ++tn)
#pragma unroll
                    for (int kk = 0; kk < 2; ++kk)
                        bfr[(r + 1) & 1][tn][kk] = *(const bf16x8*)(Bb + boff[tn][kw1][kk] + kh1 * 4224);
            }
            __builtin_amdgcn_s_setprio(1);
#pragma unroll
            for (int tm = 0; tm < 2; ++tm)
#pragma unroll
                for (int tn = 0; tn < 2; ++tn)
#pragma unroll
                    for (int kk = 0; kk < 2; ++kk)
                        acc[tm][tn] = __builtin_amdgcn_mfma_f32_32x32x16_bf16(
                            af[r % 3][tm][kk], bfr[r & 1][tn][kk], acc[tm][tn], 0, 0, 0);
            __builtin_amdgcn_s_setprio(0);
            MEMF();
        }
    }

    // ---- epilogue: 32x32 C/D: col = lane&31, row = (reg&3) + 8*(reg>>2) + 4*hi ----
#pragma unroll
    for (int tm = 0; tm < 2; ++tm)
#pragma unroll
        for (int tn = 0; tn < 2; ++tn) {
            int w = (tn << 5) + l31;
            int h = h0 + wn;
#pragma unroll
            for (int reg = 0; reg < 16; ++reg) {
                int row = (reg & 3) + ((reg >> 2) << 3) + (hi << 2);
                int o = m0 + (wm << 6) + (tm << 5) + row;
                out[(size_t)((((b << 9) + o) << 6) + h) * 64 + w] = acc[tm][tn][reg];
            }
        }
}

extern "C" void kernel_launch(void* const* d_in, const int* in_sizes, int n_in,
                              void* d_out, int out_size, void* d_ws, size_t ws_size,
                              hipStream_t stream) {
    const float* x      = (const float*)d_in[0];
    const float* style  = (const float*)d_in[1];
    const float* weight = (const float*)d_in[2];
    const float* aff_w  = (const float*)d_in[3];
    const float* aff_b  = (const float*)d_in[4];
    float* out = (float*)d_out;

    unsigned short* xmod = (unsigned short*)d_ws;            // 17,842,176 B
    unsigned short* wpk3 = xmod + 8921088;                   // 4,718,592 B (+16KB slack for tail prefetch)
    float* s_eff = (float*)((char*)d_ws + 22577152);         // 2048 f32

    hipLaunchKernelGGL(k_prep, dim3(646), dim3(512), 0, stream,
                       style, aff_w, aff_b, weight, s_eff, xmod, wpk3);
    hipLaunchKernelGGL(k_packx, dim3(8, 64, 4), dim3(256), 0, stream, x, s_eff, xmod);
    hipLaunchKernelGGL(k_conv, dim3(512), dim3(256), 0, stream, xmod, wpk3, out);
}

// Round 10
// 117.214 us; speedup vs baseline: 1.0370x; 1.0370x over previous
//
#include <hip/hip_runtime.h>

typedef __bf16 bf16x8 __attribute__((ext_vector_type(8)));
typedef float f32x4 __attribute__((ext_vector_type(4)));

#define GLDS(gp, lp) __builtin_amdgcn_global_load_lds( \
    (const __attribute__((address_space(1))) void*)(gp), \
    (__attribute__((address_space(3))) void*)(lp), 16, 0, 0)
#define WAITV(n) asm volatile("s_waitcnt vmcnt(" #n ")" ::: "memory")
#define MEMF() asm volatile("" ::: "memory")

__device__ __forceinline__ unsigned short f2bf(float f) {
    unsigned int u = __builtin_bit_cast(unsigned int, f);
    u += 0x7fffu + ((u >> 16) & 1u);
    return (unsigned short)(u >> 16);
}

// ---- Fused prep: style (blocks 0..3), border-zero (4..133), packw (134..261) ----
// packw: per block = (mt, ic): coalesced float4 loads -> LDS scatter -> linear uint4 stores.
// wpk3 layout: [mt 0..7][s=ic*9+r][wslot 0..3][lane 0..63][8ch]  (2048 el per (mt,s))
__global__ __launch_bounds__(512) void k_prep(const float* __restrict__ style,
                                              const float* __restrict__ aw,
                                              const float* __restrict__ ab,
                                              const float* __restrict__ wsrc,
                                              float* __restrict__ s_eff,
                                              unsigned short* __restrict__ xmod,
                                              unsigned short* __restrict__ wpk3) {
    __shared__ unsigned short stg[18432];   // 36 KB (packw path)
    int bid = blockIdx.x, t = threadIdx.x;
    if (bid < 4) {
        int b = bid, i = t;
        __shared__ float st[512];
        st[i] = style[(b << 9) + i];
        __syncthreads();
        const float4* row = (const float4*)(aw + ((size_t)i << 9));
        float acc = 0.f;
#pragma unroll 4
        for (int k = 0; k < 128; ++k) {
            float4 r = row[k];
            acc += r.x * st[4 * k] + r.y * st[4 * k + 1] + r.z * st[4 * k + 2] + r.w * st[4 * k + 3];
        }
        float s = acc * 0.04419417382415922f + ab[i];
        s_eff[(b << 9) + i] = s * 0.014731391274719739f;
    } else if (bid < 134) {
        int idx = (bid - 4) * 512 + t;          // 0..66559
        int cell = idx >> 6, sub = idx & 63;
        int b = cell / 260, c = cell - b * 260;
        int row, col;
        if (c < 66)       { row = 0;  col = c; }
        else if (c < 132) { row = 65; col = c - 66; }
        else { int d = c - 132; row = 1 + (d >> 1); col = (d & 1) * 65; }
        uint4 z; z.x = z.y = z.z = z.w = 0u;
        *(uint4*)(xmod + (((size_t)(b * 66 + row) * 66 + col) << 9) + (sub << 3)) = z;
    } else {
        int blk = bid - 134;                    // 0..127
        int mt = blk >> 4, ic = blk & 15;
        // load 64 o-rows x 288 f32 (ic's 32ch x 9r), coalesced float4
        int o_l = t >> 3, c8 = t & 7;           // 8 threads per o-row
        const float4* src4 = (const float4*)(wsrc + ((size_t)((mt << 6) + o_l) * 4608) + ic * 288);
        int wslot = o_l >> 4, lm = o_l & 15;
#pragma unroll
        for (int q = 0; q < 9; ++q) {
            float4 v = src4[c8 + (q << 3)];
            int e0 = (c8 + (q << 3)) << 2;
#pragma unroll
            for (int c = 0; c < 4; ++c) {
                int e = e0 + c;                 // 0..287 within o-row
                int il = e / 9, r = e - il * 9; // i_local 0..31, tap
                int lk = il >> 3, j = il & 7;
                float fv = (c == 0) ? v.x : (c == 1) ? v.y : (c == 2) ? v.z : v.w;
                stg[r * 2048 + wslot * 512 + ((lk << 4) + lm) * 8 + j] = f2bf(fv);
            }
        }
        __syncthreads();
        // 18432 el = 2304 uint4, 512 threads -> up to 5 rounds (guarded)
        unsigned short* dst = wpk3 + ((size_t)(mt * 144 + ic * 9) << 11);
#pragma unroll
        for (int q = 0; q < 5; ++q) {
            int idx = (q << 9) + t;             // uint4 index 0..2303
            if (idx < 2304)
                *(uint4*)(dst + idx * 8) = *(const uint4*)(stg + idx * 8);
        }
    }
}

// ---- packx: x (NCHW f32) -> xmod (padded NHWC bf16), modulated. Coalesced loads + LDS transpose. ----
__global__ __launch_bounds__(256) void k_packx(const float* __restrict__ x,
                                               const float* __restrict__ s_eff,
                                               unsigned short* __restrict__ xmod) {
    int b = blockIdx.z, h = blockIdx.y, i0 = blockIdx.x << 6;
    __shared__ unsigned short tile[64][72];
    int t = threadIdx.x;
    int wq = t & 15;
    int ch = t >> 4;
#pragma unroll
    for (int p = 0; p < 4; ++p) {
        int il = (p << 4) + ch;
        int i = i0 + il;
        float4 v = *(const float4*)(x + (size_t)((((b << 9) + i) << 6) + h) * 64 + (wq << 2));
        float s = s_eff[(b << 9) + i];
        union { unsigned short us[4]; uint2 u2; } u;
        u.us[0] = f2bf(v.x * s); u.us[1] = f2bf(v.y * s);
        u.us[2] = f2bf(v.z * s); u.us[3] = f2bf(v.w * s);
        *(uint2*)&tile[il][wq << 2] = u.u2;
    }
    __syncthreads();
    int ib = (t & 7) << 3;
    int wb = t >> 3;
#pragma unroll
    for (int pass = 0; pass < 2; ++pass) {
        int w = wb + (pass << 5);
        union { unsigned short us[8]; uint4 v; } u;
#pragma unroll
        for (int j = 0; j < 8; ++j) u.us[j] = tile[ib + j][w];
        *(uint4*)(xmod + (((size_t)(b * 66 + h + 1) * 66 + (w + 1)) << 9) + i0 + ib) = u.v;
    }
}

// ---- k_conv: implicit GEMM, 16x16x32 MFMA. Block 64(O) x 128(N), 4 waves of 32x64.
// Grid 1024 -> 4 blocks/CU = 16 waves/CU = 4 waves/SIMD (TLP play: 4 independent
// phase-shifted blocks per CU hide each other's stalls).
// A: coalesced global->VGPR (L2-resident fragment-linear wpk3), 3-slot rotation, 2 ahead.
// B: global_load_lds double-buffer (R6's conflict-free layout + T2 slot swizzle),
//    issued at r==4; ONE barrier per chunk at END of r==8 with uniform WAITV(8).
__global__ __launch_bounds__(256, 4) void k_conv(const unsigned short* __restrict__ xmod,
                                                 const unsigned short* __restrict__ wpk3,
                                                 float* __restrict__ out) {
    __shared__ __attribute__((aligned(128))) unsigned char lds[2][17408];

    int bid = blockIdx.x;
    // XCD map: xcd = bid&7 owns nt in [xcd*16, xcd*16+16) (B region ~2.2MB L2-resident);
    // within-xcd wid&15 selects nt, wid>>4 selects mt (16 blocks share each A-stream).
    int xcd = bid & 7, wid = bid >> 3;
    int nt = (xcd << 4) + (wid & 15);
    int mt = wid >> 4;                           // 0..7 (64-row A tiles)
    int b = nt >> 5, h0 = (nt & 31) << 1;
    int m0 = mt << 6;
    int tid = threadIdx.x;
    int lane = tid & 63;
    int wv = tid >> 6;
    int wm = wv >> 1, wn = wv & 1;               // wave tile 32(M) x 64(N)
    int lm = lane & 15, lk = lane >> 4;

    const unsigned char* xq = (const unsigned char*)xmod;

    // B global source offsets (pre-swizzled: 16B slot ^= (col>>1)&3)
    int bsrc[5];
#pragma unroll
    for (int q = 0; q < 5; ++q) {
        int c = q * 256 + tid; if (c > 1055) c = 1055;
        int cl = c >> 2, sub = c & 3;
        int row = cl / 66, col = cl - row * 66;
        int sub2 = sub ^ ((col >> 1) & 3);
        bsrc[q] = ((b * 66 + h0 + row) * 66 + col) * 1024 + (sub2 << 4);
    }

    // B LDS read offsets (swizzled slots): nl = wn*64 + fn*16 + lm
    int boff[4][3];
#pragma unroll
    for (int fn = 0; fn < 4; ++fn) {
        int nl = (wn << 6) + (fn << 4) + lm;
        int hl = nl >> 6, w = nl & 63;
#pragma unroll
        for (int kw = 0; kw < 3; ++kw) {
            int col = w + kw;
            boff[fn][kw] = hl * 4224 + col * 64 + ((lk ^ ((col >> 1) & 3)) << 4);  // + kh*4224
        }
    }

    // A fragment stream: per (mt,s): 4 wslots x 512 el; af[fm] at wslot = wm*2+fm
    const unsigned short* abase = wpk3 + ((size_t)mt * 144 << 11) + (wm << 10) + (lane << 3);

    f32x4 acc[2][4] = {};
    bf16x8 af[3][2];

    // ---- prologue: issue B[0] (GLDS), load A[0],A[1] to regs, full drain + barrier ----
    {
        unsigned char* bd = &lds[0][0] + tid * 16;
        GLDS(xq + bsrc[0], bd);
        GLDS(xq + bsrc[1], bd + 4096);
        GLDS(xq + bsrc[2], bd + 8192);
        GLDS(xq + bsrc[3], bd + 12288);
        if (wv == 0) GLDS(xq + bsrc[4], &lds[0][0] + 16384);
    }
#pragma unroll
    for (int s = 0; s < 2; ++s)
#pragma unroll
        for (int fm = 0; fm < 2; ++fm)
            af[s][fm] = *(const bf16x8*)(abase + (s << 11) + (fm << 9));
    WAITV(0);
    __builtin_amdgcn_s_barrier();
    MEMF();

#pragma unroll 1
    for (int ic = 0; ic < 16; ++ic) {
        const unsigned char* Bb = &lds[ic & 1][0];
        unsigned char* Bn = &lds[(ic + 1) & 1][0];
#pragma unroll
        for (int r = 0; r < 9; ++r) {
            int s = ic * 9 + r;
            // prefetch A[s+2] into rotation slot (r+2)%3 (wpk3 has 16KB tail slack)
            {
                const unsigned short* ap = abase + ((size_t)(s + 2) << 11);
#pragma unroll
                for (int fm = 0; fm < 2; ++fm)
                    af[(r + 2) % 3][fm] = *(const bf16x8*)(ap + (fm << 9));
            }
            if (r == 4) {   // issue B[ic+1] (ic=15: harmless dummy into dead buffer)
                int icb = (ic + 1) << 6;
                unsigned char* bd = Bn + tid * 16;
                GLDS(xq + bsrc[0] + icb, bd);
                GLDS(xq + bsrc[1] + icb, bd + 4096);
                GLDS(xq + bsrc[2] + icb, bd + 8192);
                GLDS(xq + bsrc[3] + icb, bd + 12288);
                if (wv == 0) GLDS(xq + bsrc[4] + icb, Bn + 16384);
            }
            int kh = r / 3, kw = r - kh * 3;
            bf16x8 bfr[4];
#pragma unroll
            for (int fn = 0; fn < 4; ++fn)
                bfr[fn] = *(const bf16x8*)(Bb + boff[fn][kw] + kh * 4224);
            __builtin_amdgcn_s_setprio(1);
#pragma unroll
            for (int fm = 0; fm < 2; ++fm)
#pragma unroll
                for (int fn = 0; fn < 4; ++fn)
                    acc[fm][fn] = __builtin_amdgcn_mfma_f32_16x16x32_bf16(af[r % 3][fm], bfr[fn], acc[fm][fn], 0, 0, 0);
            __builtin_amdgcn_s_setprio(0);
            MEMF();
            if (r == 8) {
                // newer-than-last-B-GLDS = A prefetches at r=5,6,7,8 = 8 loads (uniform all waves)
                WAITV(8);
                __builtin_amdgcn_s_barrier();
                MEMF();
            }
        }
    }

    // ---- epilogue: D row=(lk*4+rr) is O-sub, col=lm indexes N ----
#pragma unroll
    for (int fm = 0; fm < 2; ++fm) {
        int o = m0 + (wm << 5) + (fm << 4) + (lk << 2);
#pragma unroll
        for (int fn = 0; fn < 4; ++fn) {
            int nl = (wn << 6) + (fn << 4) + lm;
            int hl = nl >> 6, w = nl & 63;
            float* dst = out + ((((b << 9) + o) << 6) + (h0 + hl)) * 64 + w;
#pragma unroll
            for (int rr = 0; rr < 4; ++rr)
                dst[rr * 4096] = acc[fm][fn][rr];
        }
    }
}

extern "C" void kernel_launch(void* const* d_in, const int* in_sizes, int n_in,
                              void* d_out, int out_size, void* d_ws, size_t ws_size,
                              hipStream_t stream) {
    const float* x      = (const float*)d_in[0];
    const float* style  = (const float*)d_in[1];
    const float* weight = (const float*)d_in[2];
    const float* aff_w  = (const float*)d_in[3];
    const float* aff_b  = (const float*)d_in[4];
    float* out = (float*)d_out;

    unsigned short* xmod = (unsigned short*)d_ws;            // 17,842,176 B
    unsigned short* wpk3 = xmod + 8921088;                   // 4,718,592 B (+16KB tail slack)
    float* s_eff = (float*)((char*)d_ws + 22577152);         // 2048 f32

    hipLaunchKernelGGL(k_prep, dim3(262), dim3(512), 0, stream,
                       style, aff_w, aff_b, weight, s_eff, xmod, wpk3);
    hipLaunchKernelGGL(k_packx, dim3(8, 64, 4), dim3(256), 0, stream, x, s_eff, xmod);
    hipLaunchKernelGGL(k_conv, dim3(1024), dim3(256), 0, stream, xmod, wpk3, out);
}